// Round 1
// baseline (434.694 us; speedup 1.0000x reference)
//
#include <hip/hip_runtime.h>
#include <stdint.h>

// ---------------------------------------------------------------------------
// Attention: out = softmax(Q K^T) V,  N=8, S=2048, E=512, fp32 in/out.
// Strategy: bf16x2-split QK^T (hh+hl+lh MFMA) + bf16 PV, fused flash-style
// kernel with Q fragments resident in registers. ws holds bf16 planes
// (Qhi,Qlo,Khi,Klo, V^T) = 84 MB; fp32 fallback if ws is too small.
// ---------------------------------------------------------------------------

typedef __attribute__((ext_vector_type(8))) short   short8;   // 8 x bf16 (4 VGPR)
typedef __attribute__((ext_vector_type(4))) float   floatx4;  // MFMA acc

#define NBATCH 8
#define SEQ    2048
#define EDIM   512
static constexpr size_t NE = (size_t)NBATCH * SEQ * EDIM;  // 8388608 elems/tensor

__device__ __forceinline__ uint16_t f32_to_bf16_rne(float f) {
  uint32_t u = __float_as_uint(f);
  uint32_t r = u + 0x7FFFu + ((u >> 16) & 1u);   // round-to-nearest-even
  return (uint16_t)(r >> 16);
}
__device__ __forceinline__ float bf16_to_f32(uint16_t h) {
  return __uint_as_float(((uint32_t)h) << 16);
}

// --- pre-pass 1: split Q and K into hi/lo bf16 planes (row-major, same layout)
__global__ void convert_split_qk(const float* __restrict__ q, const float* __restrict__ k,
                                 uint16_t* __restrict__ qhi, uint16_t* __restrict__ qlo,
                                 uint16_t* __restrict__ khi, uint16_t* __restrict__ klo) {
  size_t i = ((size_t)blockIdx.x * blockDim.x + threadIdx.x) * 4;
  const float* src; uint16_t* dhi; uint16_t* dlo;
  if (i < NE) { src = q; dhi = qhi; dlo = qlo; }
  else        { i -= NE; src = k; dhi = khi; dlo = klo; }
  float4 x = *reinterpret_cast<const float4*>(src + i);
  ushort4 h, l;
  h.x = f32_to_bf16_rne(x.x); l.x = f32_to_bf16_rne(x.x - bf16_to_f32(h.x));
  h.y = f32_to_bf16_rne(x.y); l.y = f32_to_bf16_rne(x.y - bf16_to_f32(h.y));
  h.z = f32_to_bf16_rne(x.z); l.z = f32_to_bf16_rne(x.z - bf16_to_f32(h.z));
  h.w = f32_to_bf16_rne(x.w); l.w = f32_to_bf16_rne(x.w - bf16_to_f32(h.w));
  *reinterpret_cast<ushort4*>(dhi + i) = h;
  *reinterpret_cast<ushort4*>(dlo + i) = l;
}

// --- pre-pass 2: V[n][k][e] -> vt[n][e][k] in bf16 (so PV B-frags are contiguous)
__global__ void transpose_v_bf16(const float* __restrict__ v, uint16_t* __restrict__ vt) {
  __shared__ float tile[32][33];
  int b = blockIdx.x;                      // 8 * 64 * 16 = 8192 blocks
  int n = b >> 10, rem = b & 1023;
  int kt = rem >> 4, et = rem & 15;
  int tx = threadIdx.x & 31, ty = threadIdx.x >> 5;
  const float* src = v + ((size_t)n * SEQ + (size_t)kt * 32) * EDIM + et * 32;
#pragma unroll
  for (int i = 0; i < 4; i++) {
    int r = ty + 8 * i;
    tile[r][tx] = src[(size_t)r * EDIM + tx];
  }
  __syncthreads();
  uint16_t* dst = vt + ((size_t)n * EDIM + (size_t)et * 32) * SEQ + (size_t)kt * 32;
#pragma unroll
  for (int i = 0; i < 4; i++) {
    int rr = ty + 8 * i;
    dst[(size_t)rr * SEQ + tx] = f32_to_bf16_rne(tile[tx][rr]);
  }
}

// ---------------------------------------------------------------------------
// Fused flash attention.
// Grid: 256 blocks = (n = blk&7 [XCD swizzle], qtile = blk>>3), 512 threads (8 waves).
// BQ=64, BK=32, 64 K-tiles. Wave roles:
//   S-phase : wave w -> q-half qh=w&1 (32 rows), e-steps t==es (mod 4), es=w>>1.
//             Q frags in regs (loaded once). S = Qhi*Khi + Qlo*Khi + Qhi*Klo.
//             4 partial S planes (one per es) summed by the softmax stage.
//   PV-phase: wave w owns e-tiles g in {w, w+8, w+16, w+24}; O acc 64x64/wave.
// LDS strides: Kc 136, V^T/P 40, S 36  (8-multiples, odd dword phase -> <=2-way).
// Static LDS total = 20480 + 36864 + 5120 + 768 = 63232 B.
// ---------------------------------------------------------------------------
__launch_bounds__(512, 2)
__global__ void attn_fused(const uint16_t* __restrict__ qhi, const uint16_t* __restrict__ qlo,
                           const uint16_t* __restrict__ khi, const uint16_t* __restrict__ klo,
                           const uint16_t* __restrict__ vt, float* __restrict__ out) {
  __shared__ uint16_t region0[10240];       // union: Kc hi/lo (2*32*136) | V^T half (256*40)
  __shared__ float    s_part[4][64][36];    // per-es partial scores (fp32)
  __shared__ uint16_t p_lds[64][40];        // P (bf16) in row-major for A-frags
  __shared__ float    m_lds[64], l_lds[64], a_lds[64];

  const int tid  = threadIdx.x;
  const int lane = tid & 63, w = tid >> 6;
  const int m15  = lane & 15, q4 = lane >> 4;
  const int n    = blockIdx.x & 7, qt = blockIdx.x >> 3;
  const int q0   = qt * 64;
  const int qh   = w & 1, es = w >> 1;

  if (tid < 64) { m_lds[tid] = -3.0e38f; l_lds[tid] = 0.0f; }

  // ---- Q fragments resident in registers: [strip][chunk][hi/lo], 64 VGPRs
  short8 qf[2][4][2];
#pragma unroll
  for (int s = 0; s < 2; s++) {
    const int row = q0 + qh * 32 + s * 16 + m15;
    const uint16_t* bh = qhi + ((size_t)n * SEQ + row) * EDIM;
    const uint16_t* bl = qlo + ((size_t)n * SEQ + row) * EDIM;
#pragma unroll
    for (int c = 0; c < 4; c++) {
      const int e = (c * 4 + es) * 32 + q4 * 8;
      qf[s][c][0] = *reinterpret_cast<const short8*>(bh + e);
      qf[s][c][1] = *reinterpret_cast<const short8*>(bl + e);
    }
  }

  floatx4 oacc[4][4];                        // [q-strip][e-tile j], 64 VGPRs
#pragma unroll
  for (int s = 0; s < 4; s++)
#pragma unroll
    for (int j = 0; j < 4; j++) oacc[s][j] = (floatx4){0.f, 0.f, 0.f, 0.f};

  const int krow = tid >> 4, kgrp = tid & 15;    // Kc staging map
  const int vgrp = tid & 3;                      // V^T staging map

  for (int kt = 0; kt < 64; kt++) {
    const int k0 = kt * 32;
    floatx4 sacc[2][2];
#pragma unroll
    for (int s = 0; s < 2; s++)
#pragma unroll
      for (int ks = 0; ks < 2; ks++) sacc[s][ks] = (floatx4){0.f, 0.f, 0.f, 0.f};

    // ---- S phase: 4 e-chunks of 128
#pragma unroll
    for (int c = 0; c < 4; c++) {
      __syncthreads();                                        // region0 free
      {
        const size_t gb = ((size_t)n * SEQ + k0 + krow) * EDIM + c * 128 + kgrp * 8;
        short8 hv = *reinterpret_cast<const short8*>(khi + gb);
        short8 lv = *reinterpret_cast<const short8*>(klo + gb);
        *reinterpret_cast<short8*>(&region0[krow * 136 + kgrp * 8])        = hv;
        *reinterpret_cast<short8*>(&region0[4352 + krow * 136 + kgrp * 8]) = lv;
      }
      __syncthreads();
      short8 bh[2], bl[2];
#pragma unroll
      for (int ks = 0; ks < 2; ks++) {
        const int a = (ks * 16 + m15) * 136 + es * 32 + q4 * 8;
        bh[ks] = *reinterpret_cast<const short8*>(&region0[a]);
        bl[ks] = *reinterpret_cast<const short8*>(&region0[4352 + a]);
      }
      // hh, lh, hl — interleaved across the 4 independent accumulators
#pragma unroll
      for (int s = 0; s < 2; s++)
#pragma unroll
        for (int ks = 0; ks < 2; ks++)
          sacc[s][ks] = __builtin_amdgcn_mfma_f32_16x16x32_bf16(qf[s][c][0], bh[ks], sacc[s][ks], 0, 0, 0);
#pragma unroll
      for (int s = 0; s < 2; s++)
#pragma unroll
        for (int ks = 0; ks < 2; ks++)
          sacc[s][ks] = __builtin_amdgcn_mfma_f32_16x16x32_bf16(qf[s][c][1], bh[ks], sacc[s][ks], 0, 0, 0);
#pragma unroll
      for (int s = 0; s < 2; s++)
#pragma unroll
        for (int ks = 0; ks < 2; ks++)
          sacc[s][ks] = __builtin_amdgcn_mfma_f32_16x16x32_bf16(qf[s][c][0], bl[ks], sacc[s][ks], 0, 0, 0);
    }

    // ---- write S partials (C-layout: row = q4*4+reg, col = m15)
#pragma unroll
    for (int s = 0; s < 2; s++)
#pragma unroll
      for (int ks = 0; ks < 2; ks++)
#pragma unroll
        for (int r = 0; r < 4; r++)
          s_part[es][qh * 32 + s * 16 + q4 * 4 + r][ks * 16 + m15] = sacc[s][ks][r];
    __syncthreads();

    // ---- online softmax: 8 threads/row, 4 cols each
    {
      const int r = tid >> 3, sub = tid & 7;
      floatx4 sv = *reinterpret_cast<floatx4*>(&s_part[0][r][sub * 4]);
      sv += *reinterpret_cast<floatx4*>(&s_part[1][r][sub * 4]);
      sv += *reinterpret_cast<floatx4*>(&s_part[2][r][sub * 4]);
      sv += *reinterpret_cast<floatx4*>(&s_part[3][r][sub * 4]);
      float mx = fmaxf(fmaxf(sv[0], sv[1]), fmaxf(sv[2], sv[3]));
#pragma unroll
      for (int o = 1; o < 8; o <<= 1) mx = fmaxf(mx, __shfl_xor(mx, o));
      const float mo = m_lds[r];
      const float mn = fmaxf(mo, mx);
      floatx4 p;
      p[0] = __expf(sv[0] - mn); p[1] = __expf(sv[1] - mn);
      p[2] = __expf(sv[2] - mn); p[3] = __expf(sv[3] - mn);
      float rs = p[0] + p[1] + p[2] + p[3];
#pragma unroll
      for (int o = 1; o < 8; o <<= 1) rs += __shfl_xor(rs, o);
      if (sub == 0) {
        const float al = __expf(mo - mn);
        a_lds[r] = al; m_lds[r] = mn; l_lds[r] = l_lds[r] * al + rs;
      }
      ushort4 pu;
      pu.x = f32_to_bf16_rne(p[0]); pu.y = f32_to_bf16_rne(p[1]);
      pu.z = f32_to_bf16_rne(p[2]); pu.w = f32_to_bf16_rne(p[3]);
      *reinterpret_cast<ushort4*>(&p_lds[r][sub * 4]) = pu;
    }
    __syncthreads();

    // ---- rescale O by alpha; load P A-frags
    short8 pf[4];
#pragma unroll
    for (int s = 0; s < 4; s++) {
      floatx4 al = *reinterpret_cast<floatx4*>(&a_lds[s * 16 + q4 * 4]);
#pragma unroll
      for (int j = 0; j < 4; j++) oacc[s][j] *= al;
      pf[s] = *reinterpret_cast<const short8*>(&p_lds[s * 16 + m15][q4 * 8]);
    }

    // ---- PV: two e-halves of 256 through region0
#pragma unroll
    for (int h = 0; h < 2; h++) {
      __syncthreads();                                        // region0 free
#pragma unroll
      for (int it = 0; it < 2; it++) {
        const int el = it * 128 + (tid >> 2);
        const size_t gb = ((size_t)n * EDIM + h * 256 + el) * SEQ + k0 + vgrp * 8;
        *reinterpret_cast<short8*>(&region0[el * 40 + vgrp * 8]) =
            *reinterpret_cast<const short8*>(vt + gb);
      }
      __syncthreads();
#pragma unroll
      for (int j2 = 0; j2 < 2; j2++) {
        short8 vf = *reinterpret_cast<const short8*>(&region0[((w + 8 * j2) * 16 + m15) * 40 + q4 * 8]);
        const int j = h * 2 + j2;
#pragma unroll
        for (int s = 0; s < 4; s++)
          oacc[s][j] = __builtin_amdgcn_mfma_f32_16x16x32_bf16(pf[s], vf, oacc[s][j], 0, 0, 0);
      }
    }
  }

  __syncthreads();
  // ---- epilogue: divide by l, store fp32
#pragma unroll
  for (int s = 0; s < 4; s++) {
    floatx4 lv = *reinterpret_cast<floatx4*>(&l_lds[s * 16 + q4 * 4]);
#pragma unroll
    for (int j = 0; j < 4; j++) {
      const int col = (w + 8 * j) * 16 + m15;
#pragma unroll
      for (int r = 0; r < 4; r++) {
        const int row = s * 16 + q4 * 4 + r;
        out[((size_t)n * SEQ + q0 + row) * EDIM + col] = oacc[s][j][r] / lv[r];
      }
    }
  }
}

// ---------------------------------------------------------------------------
// Fallback (ws too small): fp32 VALU attention, one block per query row.
// Slow but correct.
// ---------------------------------------------------------------------------
__global__ void attn_fallback(const float* __restrict__ q, const float* __restrict__ k,
                              const float* __restrict__ v, float* __restrict__ out) {
  __shared__ float qrow[EDIM];
  __shared__ float sc[SEQ];
  __shared__ float red[16];
  const int tid = threadIdx.x;                    // 256
  const int n = blockIdx.x >> 11, qi = blockIdx.x & 2047;
  const int wv = tid >> 6, ln = tid & 63;
  const float* qp = q + ((size_t)n * SEQ + qi) * EDIM;
  for (int e = tid; e < EDIM; e += 256) qrow[e] = qp[e];
  __syncthreads();
  for (int kk = wv; kk < SEQ; kk += 4) {
    const float* kp = k + ((size_t)n * SEQ + kk) * EDIM;
    float s = 0.f;
    for (int e = ln; e < EDIM; e += 64) s = fmaf(qrow[e], kp[e], s);
    for (int o = 32; o > 0; o >>= 1) s += __shfl_down(s, o);
    if (ln == 0) sc[kk] = s;
  }
  __syncthreads();
  float mx = -3.0e38f;
  for (int kk = tid; kk < SEQ; kk += 256) mx = fmaxf(mx, sc[kk]);
  for (int o = 32; o > 0; o >>= 1) mx = fmaxf(mx, __shfl_down(mx, o));
  if (ln == 0) red[wv] = mx;
  __syncthreads();
  if (tid == 0) {
    float m2 = red[0];
    for (int i = 1; i < 4; i++) m2 = fmaxf(m2, red[i]);
    red[8] = m2;
  }
  __syncthreads();
  const float m = red[8];
  float ls = 0.f;
  for (int kk = tid; kk < SEQ; kk += 256) { float p = __expf(sc[kk] - m); sc[kk] = p; ls += p; }
  for (int o = 32; o > 0; o >>= 1) ls += __shfl_down(ls, o);
  if (ln == 0) red[wv] = ls;
  __syncthreads();
  if (tid == 0) { red[9] = red[0] + red[1] + red[2] + red[3]; }
  __syncthreads();
  const float linv = 1.f / red[9];
  for (int e = tid; e < EDIM; e += 256) {
    float acc = 0.f;
    const float* vp = v + ((size_t)n * SEQ) * EDIM + e;
    for (int kk = 0; kk < SEQ; kk++) acc = fmaf(sc[kk], vp[(size_t)kk * EDIM], acc);
    out[((size_t)n * SEQ + qi) * EDIM + e] = acc * linv;
  }
}

extern "C" void kernel_launch(void* const* d_in, const int* in_sizes, int n_in,
                              void* d_out, int out_size, void* d_ws, size_t ws_size,
                              hipStream_t stream) {
  const float* q = (const float*)d_in[0];
  const float* k = (const float*)d_in[1];
  const float* v = (const float*)d_in[2];
  float* out = (float*)d_out;
  const size_t need = 5 * NE * sizeof(uint16_t);   // 83,886,080 B
  if (ws_size >= need) {
    uint16_t* qhi = (uint16_t*)d_ws;
    uint16_t* qlo = qhi + NE;
    uint16_t* khi = qlo + NE;
    uint16_t* klo = khi + NE;
    uint16_t* vtp = klo + NE;
    convert_split_qk<<<16384, 256, 0, stream>>>(q, k, qhi, qlo, khi, klo);
    transpose_v_bf16<<<8192, 256, 0, stream>>>(v, vtp);
    attn_fused<<<256, 512, 0, stream>>>(qhi, qlo, khi, klo, vtp, out);
  } else {
    attn_fallback<<<16384, 256, 0, stream>>>(q, k, v, out);
  }
}